// Round 1
// baseline (592.403 us; speedup 1.0000x reference)
//
#include <hip/hip_runtime.h>
#include <hip/hip_bf16.h>
#include <stdint.h>

// ---------------- types ----------------
typedef __bf16 bf16x8 __attribute__((ext_vector_type(8)));
typedef short  s16x8  __attribute__((ext_vector_type(8)));
typedef float  f32x4  __attribute__((ext_vector_type(4)));

__device__ __forceinline__ f32x4 mfma16(s16x8 a, s16x8 b, f32x4 c) {
  return __builtin_amdgcn_mfma_f32_16x16x32_bf16(
      __builtin_bit_cast(bf16x8, a), __builtin_bit_cast(bf16x8, b), c, 0, 0, 0);
}

__device__ __forceinline__ void load_lds16(const void* g, void* l) {
  __builtin_amdgcn_global_load_lds(
      (const __attribute__((address_space(1))) void*)g,
      (__attribute__((address_space(3))) void*)l,
      16, 0, 0);
}

// ---------------- conversion kernels ----------------
__global__ void cvt_x(const float* __restrict__ in, __hip_bfloat16* __restrict__ out, int n) {
  int i = (blockIdx.x * 256 + threadIdx.x) << 2;
  if (i >= n) return;
  float4 v = *(const float4*)(in + i);
  out[i + 0] = __float2bfloat16(v.x);
  out[i + 1] = __float2bfloat16(v.y);
  out[i + 2] = __float2bfloat16(v.z);
  out[i + 3] = __float2bfloat16(v.w);
}

// W [1024][1024] f32 row-major -> Wt [1024][1024] bf16 (transposed)
__global__ void cvt_w_t(const float* __restrict__ in, __hip_bfloat16* __restrict__ out) {
  int idx = blockIdx.x * 256 + threadIdx.x;   // over 1M
  int n = idx >> 10, k = idx & 1023;
  out[idx] = __float2bfloat16(in[(k << 10) + n]);
}

// ---------------- GEMM: C[M][N] = A[M][K] * Bt[N][K]^T + bias ----------------
// OUT_MODE 0: bf16 natural [M][N]
// OUT_MODE 1: bf16 transposed V layout: [B,H,HD,S] (M=B*S rows, N=H*HD cols)
// OUT_MODE 2: fp32 natural [M][N]
template <int OUT_MODE>
__launch_bounds__(256, 2)
__global__ void gemm_bt(const __hip_bfloat16* __restrict__ A,
                        const __hip_bfloat16* __restrict__ Bt,
                        const float* __restrict__ bias,
                        void* __restrict__ Cout,
                        int M, int N, int K) {
  __shared__ __align__(16) __hip_bfloat16 As[128 * 64];
  __shared__ __align__(16) __hip_bfloat16 Bs[128 * 64];
  const int tid  = threadIdx.x;
  const int lane = tid & 63;
  const int wv   = tid >> 6;
  const int l15  = lane & 15;
  const int lhi  = lane >> 4;

  const int tilesN = N >> 7;
  const int bm = blockIdx.x / tilesN;
  const int bn = blockIdx.x % tilesN;
  const int m0 = bm << 7, n0 = bn << 7;
  const int wr = wv >> 1, wc = wv & 1;

  f32x4 acc[4][4];
  const f32x4 z = {0.f, 0.f, 0.f, 0.f};
#pragma unroll
  for (int i = 0; i < 4; ++i)
#pragma unroll
    for (int j = 0; j < 4; ++j) acc[i][j] = z;

  const int lrow = lane >> 3;                 // 0..7 row within chunk
  const int seg2 = (lane & 7) ^ lrow;         // xor-swizzled segment (16B units)
  const int nkt = K >> 6;

  for (int kt = 0; kt < nkt; ++kt) {
    __syncthreads();
    const int gk = (kt << 6) + (seg2 << 3);
#pragma unroll
    for (int j = 0; j < 4; ++j) {
      const int c = (wv << 2) + j;
      const int row = (c << 3) + lrow;
      load_lds16(A  + (size_t)(m0 + row) * K + gk, &As[c << 9]);
      load_lds16(Bt + (size_t)(n0 + row) * K + gk, &Bs[c << 9]);
    }
    __syncthreads();

#pragma unroll
    for (int kk = 0; kk < 2; ++kk) {
      s16x8 af[4], bfr[4];
#pragma unroll
      for (int mi = 0; mi < 4; ++mi) {
        const int row = (wr << 6) + (mi << 4) + l15;
        const int off = (row << 7) + ((((kk << 2) | lhi) ^ (row & 7)) << 4);
        af[mi] = *(const s16x8*)((const char*)As + off);
      }
#pragma unroll
      for (int ni = 0; ni < 4; ++ni) {
        const int row = (wc << 6) + (ni << 4) + l15;
        const int off = (row << 7) + ((((kk << 2) | lhi) ^ (row & 7)) << 4);
        bfr[ni] = *(const s16x8*)((const char*)Bs + off);
      }
#pragma unroll
      for (int mi = 0; mi < 4; ++mi)
#pragma unroll
        for (int ni = 0; ni < 4; ++ni)
          acc[mi][ni] = mfma16(af[mi], bfr[ni], acc[mi][ni]);
    }
  }

  // epilogue
#pragma unroll
  for (int ni = 0; ni < 4; ++ni) {
    const int col = n0 + (wc << 6) + (ni << 4) + l15;
    const float bval = bias ? bias[col] : 0.f;
    if (OUT_MODE == 1) {
      const int h = col >> 6, d = col & 63;
#pragma unroll
      for (int mi = 0; mi < 4; ++mi) {
        const int row0 = m0 + (wr << 6) + (mi << 4) + (lhi << 2);
#pragma unroll
        for (int r = 0; r < 4; ++r) {
          const int row = row0 + r;
          const int bb = row >> 11, s = row & 2047;
          ((__hip_bfloat16*)Cout)[(((size_t)(bb * 16 + h) * 64 + d) << 11) + s] =
              __float2bfloat16(acc[mi][ni][r] + bval);
        }
      }
    } else {
#pragma unroll
      for (int mi = 0; mi < 4; ++mi) {
        const int row0 = m0 + (wr << 6) + (mi << 4) + (lhi << 2);
#pragma unroll
        for (int r = 0; r < 4; ++r) {
          const float v = acc[mi][ni][r] + bval;
          if (OUT_MODE == 0)
            ((__hip_bfloat16*)Cout)[(size_t)(row0 + r) * N + col] = __float2bfloat16(v);
          else
            ((float*)Cout)[(size_t)(row0 + r) * N + col] = v;
        }
      }
    }
  }
}

// ---------------- flash attention ----------------
// Qb,Kb: [B*S][H*HD] bf16 natural; Vt: [B,H,HD,S] bf16; mask: [B,S] f32
// ctx out: [B*S][H*HD] bf16 natural
__launch_bounds__(256, 2)
__global__ void attn_kernel(const __hip_bfloat16* __restrict__ Qb,
                            const __hip_bfloat16* __restrict__ Kb,
                            const __hip_bfloat16* __restrict__ Vt,
                            const float* __restrict__ mask,
                            __hip_bfloat16* __restrict__ ctx) {
  __shared__ __align__(16) __hip_bfloat16 P_lds[4][16][72];  // +8 pad: 144B rows
  const int tid = threadIdx.x, lane = tid & 63, wv = tid >> 6;
  const int l15 = lane & 15, lhi = lane >> 4;
  const int blk = blockIdx.x;
  const int qt = blk & 31;
  const int h  = (blk >> 5) & 15;
  const int b  = blk >> 9;
  const int q0 = (qt << 6) + (wv << 4);

  // Q fragments (held in registers)
  s16x8 qf[2];
  {
    const __hip_bfloat16* qp =
        Qb + (size_t)(b * 2048 + q0 + l15) * 1024 + h * 64 + lhi * 8;
    qf[0] = *(const s16x8*)(qp);
    qf[1] = *(const s16x8*)(qp + 32);
  }

  f32x4 oacc[4];
  const f32x4 z = {0.f, 0.f, 0.f, 0.f};
#pragma unroll
  for (int i = 0; i < 4; ++i) oacc[i] = z;
  float mrow[4], lrow[4];
#pragma unroll
  for (int r = 0; r < 4; ++r) { mrow[r] = -1e30f; lrow[r] = 0.f; }

  const __hip_bfloat16* Kbase = Kb + (size_t)b * 2048 * 1024 + h * 64;
  const __hip_bfloat16* Vbase = Vt + ((size_t)(b * 16 + h)) * 64 * 2048;
  const float* mbase = mask + b * 2048;

  for (int t = 0; t < 32; ++t) {
    const int k0 = t << 6;
    // ---- S = Q K^T ----
    f32x4 sacc[4];
#pragma unroll
    for (int i = 0; i < 4; ++i) sacc[i] = z;
#pragma unroll
    for (int kt = 0; kt < 4; ++kt) {
      const __hip_bfloat16* kp =
          Kbase + (size_t)(k0 + kt * 16 + l15) * 1024 + lhi * 8;
      s16x8 kf0 = *(const s16x8*)(kp);
      s16x8 kf1 = *(const s16x8*)(kp + 32);
      sacc[kt] = mfma16(qf[0], kf0, sacc[kt]);
      sacc[kt] = mfma16(qf[1], kf1, sacc[kt]);
    }
    // ---- mask penalty ----
    float pen[4];
#pragma unroll
    for (int kt = 0; kt < 4; ++kt)
      pen[kt] = -1e6f * (1.0f - mbase[k0 + kt * 16 + l15]);
    // ---- online softmax (per q-row; rows live in regs, cols across 16 lanes+4 kt) ----
    float al[4];
#pragma unroll
    for (int r = 0; r < 4; ++r) {
      float v0 = sacc[0][r] * 0.125f + pen[0];
      float v1 = sacc[1][r] * 0.125f + pen[1];
      float v2 = sacc[2][r] * 0.125f + pen[2];
      float v3 = sacc[3][r] * 0.125f + pen[3];
      sacc[0][r] = v0; sacc[1][r] = v1; sacc[2][r] = v2; sacc[3][r] = v3;
      float mx = fmaxf(fmaxf(v0, v1), fmaxf(v2, v3));
      mx = fmaxf(mx, __shfl_xor(mx, 1, 16));
      mx = fmaxf(mx, __shfl_xor(mx, 2, 16));
      mx = fmaxf(mx, __shfl_xor(mx, 4, 16));
      mx = fmaxf(mx, __shfl_xor(mx, 8, 16));
      const float mn = fmaxf(mrow[r], mx);
      const float a = __expf(mrow[r] - mn);
      mrow[r] = mn;
      float s = 0.f;
#pragma unroll
      for (int kt = 0; kt < 4; ++kt) {
        const float p = __expf(sacc[kt][r] - mn);
        sacc[kt][r] = p;
        s += p;
      }
      s += __shfl_xor(s, 1, 16);
      s += __shfl_xor(s, 2, 16);
      s += __shfl_xor(s, 4, 16);
      s += __shfl_xor(s, 8, 16);
      lrow[r] = lrow[r] * a + s;
      al[r] = a;
    }
#pragma unroll
    for (int dt = 0; dt < 4; ++dt)
#pragma unroll
      for (int r = 0; r < 4; ++r) oacc[dt][r] *= al[r];
    // ---- P -> LDS (bf16, per-wave buffer, no barrier needed) ----
#pragma unroll
    for (int kt = 0; kt < 4; ++kt)
#pragma unroll
      for (int r = 0; r < 4; ++r)
        P_lds[wv][lhi * 4 + r][kt * 16 + l15] = __float2bfloat16(sacc[kt][r]);
    // ---- O += P V ----
    s16x8 pf[2];
    pf[0] = *(const s16x8*)(&P_lds[wv][l15][lhi * 8]);
    pf[1] = *(const s16x8*)(&P_lds[wv][l15][32 + lhi * 8]);
#pragma unroll
    for (int dt = 0; dt < 4; ++dt) {
      const __hip_bfloat16* vp = Vbase + (size_t)(dt * 16 + l15) * 2048 + k0 + lhi * 8;
      s16x8 vf0 = *(const s16x8*)(vp);
      s16x8 vf1 = *(const s16x8*)(vp + 32);
      oacc[dt] = mfma16(pf[0], vf0, oacc[dt]);
      oacc[dt] = mfma16(pf[1], vf1, oacc[dt]);
    }
  }

  // epilogue: ctx = O / l
  float inv[4];
#pragma unroll
  for (int r = 0; r < 4; ++r) inv[r] = 1.0f / lrow[r];
#pragma unroll
  for (int dt = 0; dt < 4; ++dt)
#pragma unroll
    for (int r = 0; r < 4; ++r)
      ctx[(size_t)(b * 2048 + q0 + lhi * 4 + r) * 1024 + h * 64 + dt * 16 + l15] =
          __float2bfloat16(oacc[dt][r] * inv[r]);
}

// ---------------- launch ----------------
extern "C" void kernel_launch(void* const* d_in, const int* in_sizes, int n_in,
                              void* d_out, int out_size, void* d_ws, size_t ws_size,
                              hipStream_t stream) {
  const float* X    = (const float*)d_in[0];
  const float* mask = (const float*)d_in[1];
  const float* Wq   = (const float*)d_in[2];
  const float* bq   = (const float*)d_in[3];
  const float* Wk   = (const float*)d_in[4];
  const float* bk   = (const float*)d_in[5];
  const float* Wv   = (const float*)d_in[6];
  const float* bvv  = (const float*)d_in[7];
  const float* Wo   = (const float*)d_in[8];
  const float* bo   = (const float*)d_in[9];
  float* out = (float*)d_out;
  char* ws = (char*)d_ws;

  __hip_bfloat16* Xb  = (__hip_bfloat16*)(ws + 0);         // 16 MiB, reused as ctx
  __hip_bfloat16* ctx = Xb;
  __hip_bfloat16* Wqt = (__hip_bfloat16*)(ws + 16777216);
  __hip_bfloat16* Wkt = (__hip_bfloat16*)(ws + 18874368);
  __hip_bfloat16* Wvt = (__hip_bfloat16*)(ws + 20971520);
  __hip_bfloat16* Wot = (__hip_bfloat16*)(ws + 23068672);
  __hip_bfloat16* Qb  = (__hip_bfloat16*)(ws + 25165824);
  __hip_bfloat16* Kb  = (__hip_bfloat16*)(ws + 41943040);
  __hip_bfloat16* Vt  = (__hip_bfloat16*)(ws + 58720256);

  cvt_x<<<8192, 256, 0, stream>>>(X, Xb, 8388608);
  cvt_w_t<<<4096, 256, 0, stream>>>(Wq, Wqt);
  cvt_w_t<<<4096, 256, 0, stream>>>(Wk, Wkt);
  cvt_w_t<<<4096, 256, 0, stream>>>(Wv, Wvt);
  cvt_w_t<<<4096, 256, 0, stream>>>(Wo, Wot);

  gemm_bt<0><<<512, 256, 0, stream>>>(Xb, Wqt, bq,  Qb,  8192, 1024, 1024);
  gemm_bt<0><<<512, 256, 0, stream>>>(Xb, Wkt, bk,  Kb,  8192, 1024, 1024);
  gemm_bt<1><<<512, 256, 0, stream>>>(Xb, Wvt, bvv, Vt,  8192, 1024, 1024);

  attn_kernel<<<2048, 256, 0, stream>>>(Qb, Kb, Vt, mask, ctx);

  gemm_bt<2><<<512, 256, 0, stream>>>(ctx, Wot, bo, out, 8192, 1024, 1024);
}

// Round 2
// 369.657 us; speedup vs baseline: 1.6026x; 1.6026x over previous
//
#include <hip/hip_runtime.h>
#include <hip/hip_bf16.h>
#include <stdint.h>

// ---------------- types ----------------
typedef __bf16 bf16x8 __attribute__((ext_vector_type(8)));
typedef short  s16x8  __attribute__((ext_vector_type(8)));
typedef float  f32x4  __attribute__((ext_vector_type(4)));
typedef float  f32x16 __attribute__((ext_vector_type(16)));
typedef unsigned int u32x2 __attribute__((ext_vector_type(2)));
typedef unsigned int u32x4 __attribute__((ext_vector_type(4)));

__device__ __forceinline__ f32x4 mfma16(s16x8 a, s16x8 b, f32x4 c) {
  return __builtin_amdgcn_mfma_f32_16x16x32_bf16(
      __builtin_bit_cast(bf16x8, a), __builtin_bit_cast(bf16x8, b), c, 0, 0, 0);
}
__device__ __forceinline__ f32x16 mfma32(s16x8 a, s16x8 b, f32x16 c) {
  return __builtin_amdgcn_mfma_f32_32x32x16_bf16(
      __builtin_bit_cast(bf16x8, a), __builtin_bit_cast(bf16x8, b), c, 0, 0, 0);
}

__device__ __forceinline__ void load_lds16(const void* g, void* l) {
  __builtin_amdgcn_global_load_lds(
      (const __attribute__((address_space(1))) void*)g,
      (__attribute__((address_space(3))) void*)l,
      16, 0, 0);
}

__device__ __forceinline__ float exp2fast(float x) {
  float r; asm("v_exp_f32 %0, %1" : "=v"(r) : "v"(x)); return r;
}
__device__ __forceinline__ unsigned cvtpk_bf16(float lo, float hi) {
  unsigned r; asm("v_cvt_pk_bf16_f32 %0, %1, %2" : "=v"(r) : "v"(lo), "v"(hi)); return r;
}
// x := lanes<32: a | lanes>=32: b[lane-32] ; y := lanes<32: a[lane+32] | lanes>=32: b
__device__ __forceinline__ void plswap2(unsigned a, unsigned b, int hi,
                                        unsigned& x, unsigned& y) {
#if __has_builtin(__builtin_amdgcn_permlane32_swap)
  auto r = __builtin_amdgcn_permlane32_swap(a, b, false, false);
  x = (unsigned)r[0]; y = (unsigned)r[1];
#else
  unsigned ax = (unsigned)__shfl_xor((int)a, 32);
  unsigned bx = (unsigned)__shfl_xor((int)b, 32);
  x = hi ? bx : a;
  y = hi ? b : ax;
#endif
}

// ---------------- conversion kernels ----------------
__global__ void cvt_x(const float* __restrict__ in, __hip_bfloat16* __restrict__ out, int n) {
  int i = (blockIdx.x * 256 + threadIdx.x) << 2;
  if (i >= n) return;
  float4 v = *(const float4*)(in + i);
  out[i + 0] = __float2bfloat16(v.x);
  out[i + 1] = __float2bfloat16(v.y);
  out[i + 2] = __float2bfloat16(v.z);
  out[i + 3] = __float2bfloat16(v.w);
}

__global__ void cvt_w_t(const float* __restrict__ in, __hip_bfloat16* __restrict__ out) {
  int idx = blockIdx.x * 256 + threadIdx.x;
  int n = idx >> 10, k = idx & 1023;
  out[idx] = __float2bfloat16(in[(k << 10) + n]);
}

// ---------------- GEMM (unchanged from passing r1) ----------------
template <int OUT_MODE>
__launch_bounds__(256, 2)
__global__ void gemm_bt(const __hip_bfloat16* __restrict__ A,
                        const __hip_bfloat16* __restrict__ Bt,
                        const float* __restrict__ bias,
                        void* __restrict__ Cout,
                        int M, int N, int K) {
  __shared__ __align__(16) __hip_bfloat16 As[128 * 64];
  __shared__ __align__(16) __hip_bfloat16 Bs[128 * 64];
  const int tid  = threadIdx.x;
  const int lane = tid & 63;
  const int wv   = tid >> 6;
  const int l15  = lane & 15;
  const int lhi  = lane >> 4;

  const int tilesN = N >> 7;
  const int bm = blockIdx.x / tilesN;
  const int bn = blockIdx.x % tilesN;
  const int m0 = bm << 7, n0 = bn << 7;
  const int wr = wv >> 1, wc = wv & 1;

  f32x4 acc[4][4];
  const f32x4 z = {0.f, 0.f, 0.f, 0.f};
#pragma unroll
  for (int i = 0; i < 4; ++i)
#pragma unroll
    for (int j = 0; j < 4; ++j) acc[i][j] = z;

  const int lrow = lane >> 3;
  const int seg2 = (lane & 7) ^ lrow;
  const int nkt = K >> 6;

  for (int kt = 0; kt < nkt; ++kt) {
    __syncthreads();
    const int gk = (kt << 6) + (seg2 << 3);
#pragma unroll
    for (int j = 0; j < 4; ++j) {
      const int c = (wv << 2) + j;
      const int row = (c << 3) + lrow;
      load_lds16(A  + (size_t)(m0 + row) * K + gk, &As[c << 9]);
      load_lds16(Bt + (size_t)(n0 + row) * K + gk, &Bs[c << 9]);
    }
    __syncthreads();

#pragma unroll
    for (int kk = 0; kk < 2; ++kk) {
      s16x8 af[4], bfr[4];
#pragma unroll
      for (int mi = 0; mi < 4; ++mi) {
        const int row = (wr << 6) + (mi << 4) + l15;
        const int off = (row << 7) + ((((kk << 2) | lhi) ^ (row & 7)) << 4);
        af[mi] = *(const s16x8*)((const char*)As + off);
      }
#pragma unroll
      for (int ni = 0; ni < 4; ++ni) {
        const int row = (wc << 6) + (ni << 4) + l15;
        const int off = (row << 7) + ((((kk << 2) | lhi) ^ (row & 7)) << 4);
        bfr[ni] = *(const s16x8*)((const char*)Bs + off);
      }
#pragma unroll
      for (int mi = 0; mi < 4; ++mi)
#pragma unroll
        for (int ni = 0; ni < 4; ++ni)
          acc[mi][ni] = mfma16(af[mi], bfr[ni], acc[mi][ni]);
    }
  }

#pragma unroll
  for (int ni = 0; ni < 4; ++ni) {
    const int col = n0 + (wc << 6) + (ni << 4) + l15;
    const float bval = bias ? bias[col] : 0.f;
    if (OUT_MODE == 1) {
      const int h = col >> 6, d = col & 63;
#pragma unroll
      for (int mi = 0; mi < 4; ++mi) {
        const int row0 = m0 + (wr << 6) + (mi << 4) + (lhi << 2);
#pragma unroll
        for (int r = 0; r < 4; ++r) {
          const int row = row0 + r;
          const int bb = row >> 11, s = row & 2047;
          ((__hip_bfloat16*)Cout)[(((size_t)(bb * 16 + h) * 64 + d) << 11) + s] =
              __float2bfloat16(acc[mi][ni][r] + bval);
        }
      }
    } else {
#pragma unroll
      for (int mi = 0; mi < 4; ++mi) {
        const int row0 = m0 + (wr << 6) + (mi << 4) + (lhi << 2);
#pragma unroll
        for (int r = 0; r < 4; ++r) {
          const float v = acc[mi][ni][r] + bval;
          if (OUT_MODE == 0)
            ((__hip_bfloat16*)Cout)[(size_t)(row0 + r) * N + col] = __float2bfloat16(v);
          else
            ((float*)Cout)[(size_t)(row0 + r) * N + col] = v;
        }
      }
    }
  }
}

// ---------------- flash attention, 32x32 swapped-operand ----------------
// Qb,Kb: [B*S][1024] bf16; Vt: [B,H,HD,S] bf16; mask: [B,S] f32
// ctx: [B*S][1024] bf16
// Per warp: 32 q-rows. lane&31 = q throughout; softmax entirely per-lane.
__launch_bounds__(256, 2)
__global__ void attn32(const __hip_bfloat16* __restrict__ Qb,
                       const __hip_bfloat16* __restrict__ Kb,
                       const __hip_bfloat16* __restrict__ Vt,
                       const float* __restrict__ mask,
                       __hip_bfloat16* __restrict__ ctx) {
  __shared__ float pen_lds[2048];
  const int tid = threadIdx.x;
  const int lane = tid & 63, wv = tid >> 6;
  const int l31 = lane & 31, hi = lane >> 5;

  // XCD-bijective swizzle: each XCD owns 8 consecutive (b,h) pairs (1024%8==0)
  const int bid = blockIdx.x;
  const int lb = (bid & 7) * 128 + (bid >> 3);
  const int qt = lb & 15;
  const int bh = lb >> 4;
  const int h = bh & 15, b = bh >> 4;

  // mask penalty in exp2 domain: pen2[k] = -1e6*log2(e)*(1-mask[b][k])
  {
    const float* mrow = mask + b * 2048;
    const int i0 = tid * 4;
    float4 m0 = *(const float4*)(mrow + i0);
    float4 m1 = *(const float4*)(mrow + i0 + 1024);
    pen_lds[i0 + 0] = -1442695.04f * (1.f - m0.x);
    pen_lds[i0 + 1] = -1442695.04f * (1.f - m0.y);
    pen_lds[i0 + 2] = -1442695.04f * (1.f - m0.z);
    pen_lds[i0 + 3] = -1442695.04f * (1.f - m0.w);
    pen_lds[i0 + 1024] = -1442695.04f * (1.f - m1.x);
    pen_lds[i0 + 1025] = -1442695.04f * (1.f - m1.y);
    pen_lds[i0 + 1026] = -1442695.04f * (1.f - m1.z);
    pen_lds[i0 + 1027] = -1442695.04f * (1.f - m1.w);
  }
  __syncthreads();

  const int q0 = qt * 128 + wv * 32;

  // Q fragments (B-operand: col=q=lane&31, k = hi*8+reg within each 16-d block)
  s16x8 qf[4];
  {
    const __hip_bfloat16* qp =
        Qb + (size_t)(b * 2048 + q0 + l31) * 1024 + h * 64 + hi * 8;
#pragma unroll
    for (int d = 0; d < 4; ++d) qf[d] = *(const s16x8*)(qp + d * 16);
  }

  const __hip_bfloat16* Kbase = Kb + (size_t)b * 2048 * 1024 + h * 64 + hi * 8;
  const __hip_bfloat16* Vbase =
      Vt + (size_t)(b * 16 + h) * 64 * 2048 + (size_t)l31 * 2048 + hi * 8;

  f32x16 oa0, oa1;
#pragma unroll
  for (int i = 0; i < 16; ++i) { oa0[i] = 0.f; oa1[i] = 0.f; }
  float mrun = -1e30f, lrun = 0.f;

  // K fragments, double-buffered (A-operand: row=k=lane&31, k-contract = hi*8+reg)
  s16x8 kfA[8], kfB[8];
#pragma unroll
  for (int i = 0; i < 8; ++i)
    kfA[i] = *(const s16x8*)(Kbase + (size_t)((i >> 2) * 32 + l31) * 1024 + (i & 3) * 16);

  auto step = [&](int t, s16x8* kfC, s16x8* kfN) {
    const int k0 = t << 6;
    // V fragments for dt=0 (d=0..31), issued early — consumed after softmax
    s16x8 vf0[4];
#pragma unroll
    for (int ks = 0; ks < 4; ++ks)
      vf0[ks] = *(const s16x8*)(Vbase + k0 + ks * 16);

    // ---- S^T = K Q^T : 2 k-subtiles x 4 d-blocks ----
    f32x16 sa[2];
#pragma unroll
    for (int i = 0; i < 16; ++i) { sa[0][i] = 0.f; sa[1][i] = 0.f; }
#pragma unroll
    for (int d = 0; d < 4; ++d) sa[0] = mfma32(kfC[d], qf[d], sa[0]);
#pragma unroll
    for (int d = 0; d < 4; ++d) sa[1] = mfma32(kfC[4 + d], qf[d], sa[1]);

    // prefetch next K tile (consumed next iteration)
    const int k0n = ((t + 1) & 31) << 6;
#pragma unroll
    for (int i = 0; i < 8; ++i)
      kfN[i] = *(const s16x8*)(Kbase + (size_t)(k0n + (i >> 2) * 32 + l31) * 1024 + (i & 3) * 16);

    // V fragments for dt=1 (d=32..63)
    s16x8 vf1[4];
#pragma unroll
    for (int ks = 0; ks < 4; ++ks)
      vf1[ks] = *(const s16x8*)(Vbase + 32 * 2048 + k0 + ks * 16);

    // ---- softmax (fully per-lane; lane owns q=lane&31, 32 k-values) ----
    // sacc reg r of subtile s -> k = 32*s + 8*(r>>2) + 4*hi + (r&3)
    float pq[32];
#pragma unroll
    for (int s = 0; s < 2; ++s)
#pragma unroll
      for (int a = 0; a < 4; ++a) {
        const f32x4 pn = *(const f32x4*)&pen_lds[k0 + s * 32 + a * 8 + hi * 4];
#pragma unroll
        for (int r = 0; r < 4; ++r)
          pq[s * 16 + a * 4 + r] = fmaf(sa[s][a * 4 + r], 0.18033688011112042f, pn[r]);
      }
    float t16[16];
#pragma unroll
    for (int i = 0; i < 16; ++i) t16[i] = fmaxf(pq[i], pq[i + 16]);
#pragma unroll
    for (int i = 0; i < 8; ++i) t16[i] = fmaxf(t16[i], t16[i + 8]);
#pragma unroll
    for (int i = 0; i < 4; ++i) t16[i] = fmaxf(t16[i], t16[i + 4]);
    float mx = fmaxf(fmaxf(t16[0], t16[1]), fmaxf(t16[2], t16[3]));
    mx = fmaxf(mx, __shfl_xor(mx, 32));
    const float mnew = fmaxf(mrun, mx);
    const float aa = exp2fast(mrun - mnew);
    mrun = mnew;
    float s4[4] = {0.f, 0.f, 0.f, 0.f};
#pragma unroll
    for (int i = 0; i < 32; ++i) {
      const float p = exp2fast(pq[i] - mnew);
      pq[i] = p;
      s4[i & 3] += p;
    }
    float sum = (s4[0] + s4[1]) + (s4[2] + s4[3]);
    sum += __shfl_xor(sum, 32);
    lrun = lrun * aa + sum;
#pragma unroll
    for (int i = 0; i < 16; ++i) { oa0[i] *= aa; oa1[i] *= aa; }

    // ---- pack P -> bf16 B-fragments (cvt_pk + permlane32_swap) ----
    s16x8 pb[4];
#pragma unroll
    for (int ks = 0; ks < 4; ++ks) {
      const int base = (ks >> 1) * 16 + (ks & 1) * 8;
      const unsigned wa0 = cvtpk_bf16(pq[base + 0], pq[base + 1]);
      const unsigned wa1 = cvtpk_bf16(pq[base + 2], pq[base + 3]);
      const unsigned wb0 = cvtpk_bf16(pq[base + 4], pq[base + 5]);
      const unsigned wb1 = cvtpk_bf16(pq[base + 6], pq[base + 7]);
      unsigned x0, y0, x1, y1;
      plswap2(wa0, wb0, hi, x0, y0);
      plswap2(wa1, wb1, hi, x1, y1);
      u32x4 u = {x0, x1, y0, y1};
      pb[ks] = __builtin_bit_cast(s16x8, u);
    }

    // ---- O^T += V^T P^T : rows=d (reg-mapped), cols=q=lane&31 ----
#pragma unroll
    for (int ks = 0; ks < 4; ++ks) oa0 = mfma32(vf0[ks], pb[ks], oa0);
#pragma unroll
    for (int ks = 0; ks < 4; ++ks) oa1 = mfma32(vf1[ks], pb[ks], oa1);
  };

  for (int t = 0; t < 32; t += 2) {
    step(t, kfA, kfB);
    step(t + 1, kfB, kfA);
  }

  // ---- epilogue: ctx[q][h*64+d] = O[d][q] / l ----
  const float inv = 1.0f / lrun;
  __hip_bfloat16* cp = ctx + (size_t)(b * 2048 + q0 + l31) * 1024 + h * 64 + hi * 4;
#pragma unroll
  for (int dt = 0; dt < 2; ++dt) {
#pragma unroll
    for (int g = 0; g < 4; ++g) {
      const float v0 = (dt ? oa1[4 * g + 0] : oa0[4 * g + 0]) * inv;
      const float v1 = (dt ? oa1[4 * g + 1] : oa0[4 * g + 1]) * inv;
      const float v2 = (dt ? oa1[4 * g + 2] : oa0[4 * g + 2]) * inv;
      const float v3 = (dt ? oa1[4 * g + 3] : oa0[4 * g + 3]) * inv;
      u32x2 u;
      u[0] = cvtpk_bf16(v0, v1);
      u[1] = cvtpk_bf16(v2, v3);
      *(u32x2*)(cp + dt * 32 + g * 8) = u;
    }
  }
}

// ---------------- launch ----------------
extern "C" void kernel_launch(void* const* d_in, const int* in_sizes, int n_in,
                              void* d_out, int out_size, void* d_ws, size_t ws_size,
                              hipStream_t stream) {
  const float* X    = (const float*)d_in[0];
  const float* mask = (const float*)d_in[1];
  const float* Wq   = (const float*)d_in[2];
  const float* bq   = (const float*)d_in[3];
  const float* Wk   = (const float*)d_in[4];
  const float* bk   = (const float*)d_in[5];
  const float* Wv   = (const float*)d_in[6];
  const float* bvv  = (const float*)d_in[7];
  const float* Wo   = (const float*)d_in[8];
  const float* bo   = (const float*)d_in[9];
  float* out = (float*)d_out;
  char* ws = (char*)d_ws;

  __hip_bfloat16* Xb  = (__hip_bfloat16*)(ws + 0);         // 16 MiB, reused as ctx
  __hip_bfloat16* ctx = Xb;
  __hip_bfloat16* Wqt = (__hip_bfloat16*)(ws + 16777216);
  __hip_bfloat16* Wkt = (__hip_bfloat16*)(ws + 18874368);
  __hip_bfloat16* Wvt = (__hip_bfloat16*)(ws + 20971520);
  __hip_bfloat16* Wot = (__hip_bfloat16*)(ws + 23068672);
  __hip_bfloat16* Qb  = (__hip_bfloat16*)(ws + 25165824);
  __hip_bfloat16* Kb  = (__hip_bfloat16*)(ws + 41943040);
  __hip_bfloat16* Vt  = (__hip_bfloat16*)(ws + 58720256);

  cvt_x<<<8192, 256, 0, stream>>>(X, Xb, 8388608);
  cvt_w_t<<<4096, 256, 0, stream>>>(Wq, Wqt);
  cvt_w_t<<<4096, 256, 0, stream>>>(Wk, Wkt);
  cvt_w_t<<<4096, 256, 0, stream>>>(Wv, Wvt);
  cvt_w_t<<<4096, 256, 0, stream>>>(Wo, Wot);

  gemm_bt<0><<<512, 256, 0, stream>>>(Xb, Wqt, bq,  Qb,  8192, 1024, 1024);
  gemm_bt<0><<<512, 256, 0, stream>>>(Xb, Wkt, bk,  Kb,  8192, 1024, 1024);
  gemm_bt<1><<<512, 256, 0, stream>>>(Xb, Wvt, bvv, Vt,  8192, 1024, 1024);

  attn32<<<1024, 256, 0, stream>>>(Qb, Kb, Vt, mask, ctx);

  gemm_bt<2><<<512, 256, 0, stream>>>(ctx, Wot, bo, out, 8192, 1024, 1024);
}